// Round 10
// baseline (3803.671 us; speedup 1.0000x reference)
//
#include <hip/hip_runtime.h>
#include <math.h>

#define A_PL 22
#define F_IN_ 16
#define T_LEN 256
#define NBLK_SEQ 64

__device__ __forceinline__ float sigmoidf_(float x) { return 1.f / (1.f + __expf(-x)); }

// Cross-XCD-safe handoff (per-op agent-scope atomics; validated across rounds,
// absmax 0.0 every passing run).
__device__ __forceinline__ void gstore(float* p, float v) {
  __hip_atomic_store(p, v, __ATOMIC_RELAXED, __HIP_MEMORY_SCOPE_AGENT);
}
__device__ __forceinline__ float gload(const float* p) {
  return __hip_atomic_load(p, __ATOMIC_RELAXED, __HIP_MEMORY_SCOPE_AGENT);
}

// Dataflow wait (R4..R9-validated): acquire-poll + agent-acquire fence so
// subsequent PLAIN vector loads see released data.
__device__ __forceinline__ void dwait(unsigned* arr, int tlo, int thi) {
  if (threadIdx.x < 64) {
    const int lane = threadIdx.x;
    int t = (lane < 32) ? tlo : thi;
    if (t < 0) t = 0;
    const unsigned tu = (unsigned)t;
    while (__hip_atomic_load(arr + lane * 32, __ATOMIC_ACQUIRE,
                             __HIP_MEMORY_SCOPE_AGENT) < tu) {
      __builtin_amdgcn_s_sleep(1);
    }
  }
  __syncthreads();
  __builtin_amdgcn_fence(__ATOMIC_ACQUIRE, "agent");
}

// Half-wait: poll ONE 32-flag group (base=0: L0 blocks, base=32: L1 blocks).
// Same acquire-poll + fence discipline as dwait.
__device__ __forceinline__ void dwait_half(unsigned* arr, int base, int tgt) {
  if (threadIdx.x < 32) {
    const unsigned tu = (unsigned)(tgt < 0 ? 0 : tgt);
    while (__hip_atomic_load(arr + (base + threadIdx.x) * 32, __ATOMIC_ACQUIRE,
                             __HIP_MEMORY_SCOPE_AGENT) < tu) {
      __builtin_amdgcn_s_sleep(1);
    }
  }
  __syncthreads();
  __builtin_amdgcn_fence(__ATOMIC_ACQUIRE, "agent");
}

// DPP cross-lane ops, all on the VALU pipe (no LDS). (R7/R9-validated.)
__device__ __forceinline__ float dpp_xor1(float v) {
  int r = __builtin_amdgcn_mov_dpp(__builtin_bit_cast(int, v), 0xB1, 0xF, 0xF, true);
  return __builtin_bit_cast(float, r);
}
__device__ __forceinline__ float dpp_xor2(float v) {
  int r = __builtin_amdgcn_mov_dpp(__builtin_bit_cast(int, v), 0x4E, 0xF, 0xF, true);
  return __builtin_bit_cast(float, r);
}
__device__ __forceinline__ float dpp_ror4(float v) {
  int r = __builtin_amdgcn_mov_dpp(__builtin_bit_cast(int, v), 0x124, 0xF, 0xF, true);
  return __builtin_bit_cast(float, r);
}
__device__ __forceinline__ float dpp_ror8(float v) {
  int r = __builtin_amdgcn_mov_dpp(__builtin_bit_cast(int, v), 0x128, 0xF, 0xF, true);
  return __builtin_bit_cast(float, r);
}

// seq_lengths: int64 or int32. True values in [128,256], never 0 =>
// little-endian int64 has lens32[1]==0.
__device__ __forceinline__ int read_len(const int* __restrict__ lens, int b) {
  return (lens[1] == 0) ? lens[2 * b] : lens[b];
}

// ---------------------------------------------------------------------------
// Kernel 1: fused GAT (R4..R9 version, passed; unchanged this round).
// Output written TRANSPOSED as xT[t][c][b].
// ---------------------------------------------------------------------------
__global__ __launch_bounds__(256) void gat_naive(
    const float* __restrict__ feat, const int* __restrict__ lens,
    const float* __restrict__ W1, const float* __restrict__ as1,
    const float* __restrict__ ad1, const float* __restrict__ b1,
    const float* __restrict__ W2, const float* __restrict__ as2,
    const float* __restrict__ ad2, const float* __restrict__ b2,
    float* __restrict__ xT)
{
  const int n = blockIdx.x;
  const int tid = threadIdx.x;
  const int bb = n >> 8;          // batch
  const int tt = n & 255;         // time
  if (tt >= read_len(lens, bb)) { // masked frame: pooled = 0
    if (tid < 128) xT[((size_t)tt * 128 + tid) * 32 + bb] = 0.f;
    return;
  }

  __shared__ float xs[352];       // x [22][16]
  __shared__ float hbuf[2816];    // per-head h [22][128]; later h2 [22][128]
  __shared__ float x2s[11264];    // GAT1 output [22][512] (relu'd)
  __shared__ float asrc[22], adst[22], alpha[484];

  for (int i = tid; i < 352; i += 256) xs[i] = feat[(size_t)n * 352 + i];
  __syncthreads();

  const int c_ = tid & 127;
  const int ap_ = tid >> 7;       // a-parity for this thread

  for (int hd = 0; hd < 4; hd++) {
    {
      float wreg[16];
      #pragma unroll
      for (int f = 0; f < 16; f++) wreg[f] = W1[f * 512 + hd * 128 + c_];
      #pragma unroll
      for (int q = 0; q < 11; q++) {
        const int a = ap_ + 2 * q;
        float acc = 0.f;
        #pragma unroll
        for (int f4 = 0; f4 < 4; f4++) {
          const float4 x4 = *(const float4*)(xs + a * 16 + f4 * 4);
          acc += x4.x * wreg[f4 * 4] + x4.y * wreg[f4 * 4 + 1]
               + x4.z * wreg[f4 * 4 + 2] + x4.w * wreg[f4 * 4 + 3];
        }
        hbuf[a * 128 + c_] = acc;
      }
    }
    __syncthreads();
    if (tid < 44) {
      int a = tid >> 1;
      const float* av = (tid & 1) ? ad1 : as1;
      float s = 0.f;
      for (int c = 0; c < 128; c++) s += hbuf[a * 128 + c] * av[hd * 128 + c];
      ((tid & 1) ? adst : asrc)[a] = s;
    }
    __syncthreads();
    if (tid < 22) {
      float ev[22], m = -1e30f;
      for (int j = 0; j < 22; j++) {
        float e = adst[tid] + asrc[j];
        e = (e > 0.f) ? e : 0.2f * e;
        ev[j] = e; if (e > m) m = e;
      }
      float s = 0.f;
      for (int j = 0; j < 22; j++) { ev[j] = __expf(ev[j] - m); s += ev[j]; }
      float inv = 1.f / s;
      for (int j = 0; j < 22; j++) alpha[tid * 22 + j] = ev[j] * inv;
    }
    __syncthreads();
    for (int i = tid; i < 2816; i += 256) {
      int a = i >> 7, c = i & 127;
      float acc = 0.f;
      for (int j = 0; j < 22; j++) acc += alpha[a * 22 + j] * hbuf[j * 128 + c];
      x2s[a * 512 + hd * 128 + c] = fmaxf(acc + b1[hd * 128 + c], 0.f);
    }
    __syncthreads();
  }

  // ---- W2 matmul: hbuf = relu-in of GAT2 h = x2s @ W2 ----
  {
    float acc[11];
    #pragma unroll
    for (int q = 0; q < 11; q++) acc[q] = 0.f;
    for (int k = 0; k < 512; k += 4) {
      const float w0 = W2[(size_t)(k + 0) * 128 + c_];
      const float w1 = W2[(size_t)(k + 1) * 128 + c_];
      const float w2 = W2[(size_t)(k + 2) * 128 + c_];
      const float w3 = W2[(size_t)(k + 3) * 128 + c_];
      #pragma unroll
      for (int q = 0; q < 11; q++) {
        const float4 x4 = *(const float4*)(x2s + (ap_ + 2 * q) * 512 + k);
        acc[q] += x4.x * w0 + x4.y * w1 + x4.z * w2 + x4.w * w3;
      }
    }
    #pragma unroll
    for (int q = 0; q < 11; q++) hbuf[(ap_ + 2 * q) * 128 + c_] = acc[q];
  }
  __syncthreads();
  if (tid < 44) {
    int a = tid >> 1;
    const float* av = (tid & 1) ? ad2 : as2;
    float s = 0.f;
    for (int c = 0; c < 128; c++) s += hbuf[a * 128 + c] * av[c];
    ((tid & 1) ? adst : asrc)[a] = s;
  }
  __syncthreads();
  if (tid < 22) {
    float ev[22], m = -1e30f;
    for (int j = 0; j < 22; j++) {
      float e = adst[tid] + asrc[j];
      e = (e > 0.f) ? e : 0.2f * e;
      ev[j] = e; if (e > m) m = e;
    }
    float s = 0.f;
    for (int j = 0; j < 22; j++) { ev[j] = __expf(ev[j] - m); s += ev[j]; }
    float inv = 1.f / s;
    for (int j = 0; j < 22; j++) alpha[tid * 22 + j] = ev[j] * inv;
  }
  __syncthreads();
  if (tid < 128) {
    float s = 0.f;
    for (int a = 0; a < 22; a++) {
      float v = b2[tid];
      for (int j = 0; j < 22; j++) v += alpha[a * 22 + j] * hbuf[j * 128 + tid];
      s += fmaxf(v, 0.f);
    }
    xT[((size_t)tt * 128 + tid) * 32 + bb] = s * (1.f / 22.f);
  }
}

// ---------------------------------------------------------------------------
// Kernel 2, L0 body: R9 verbatim (KK=384). Not on the critical path.
// ---------------------------------------------------------------------------
__device__ __forceinline__ void lstm_body_l0(
    const int j0, const float* __restrict__ xT,
    const float* __restrict__ Wih, const float* __restrict__ Whh,
    const float* __restrict__ bih, const float* __restrict__ bhh,
    const int* __restrict__ lens,
    float* __restrict__ h0T, float* __restrict__ h1T,
    unsigned* __restrict__ arr, const int bid,
    float* __restrict__ wlds, float* __restrict__ hs, float* __restrict__ gates)
{
  constexpr int NK = 24;
  const int tid = threadIdx.x;
  const int kp = tid & 15;
  const int cg = (tid >> 4) & 7;
  const int bg = tid >> 7;
  const int c0 = cg * 4;
  const int b0 = bg * 8;
  const int sw = (kp & 7) << 2;
  const float* hpA = hs + kp * 32 + (b0 ^ sw);
  const float* hpB = hs + kp * 32 + ((b0 + 4) ^ sw);
  const float* wp  = wlds + kp * 32 + (c0 ^ sw);

  for (int c = 0; c < 32; c++) {
    const int r = ((c >> 3) << 8) + j0 + (c & 7);
    for (int k = tid; k < 384; k += 512) {
      float v = (k < 128) ? Wih[r * 128 + k] : Whh[r * 256 + (k - 128)];
      wlds[k * 32 + (c ^ ((k & 7) << 2))] = v;
    }
  }

  const int nb = tid >> 3, njl = tid & 7;
  float bb0 = 0.f, bb1 = 0.f, bb2 = 0.f, bb3 = 0.f;
  int len_b = T_LEN;
  if (tid < 256) {
    const int j = j0 + njl;
    bb0 = bih[j]       + bhh[j];
    bb1 = bih[256 + j] + bhh[256 + j];
    bb2 = bih[512 + j] + bhh[512 + j];
    bb3 = bih[768 + j] + bhh[768 + j];
    len_b = read_len(lens, nb);
  }
  float creg = 0.f;

  for (int p = 0; p <= T_LEN - 1; p++) {
    if (p > 0) dwait(arr, p, p - 2);

    {
      const float* xp = xT + (size_t)p * 4096;
      const float* s0 = h0T + (size_t)((p + 3) & 3) * 8192;  // (p-1)&3
      #pragma unroll
      for (int i = tid; i < 3072; i += 512) {
        const int k = i >> 3, b4 = (i & 7) << 2;
        const float4 v = (k < 128)
            ? *(const float4*)(xp + (k << 5) + b4)
            : *(const float4*)(s0 + ((k - 128) << 5) + b4);
        *(float4*)(hs + (k << 5) + (b4 ^ ((k & 7) << 2))) = v;
      }
      __syncthreads();

      float a[4][8] = {};
      #pragma unroll
      for (int t = 0; t < NK; t++) {
        const float4 hA = *(const float4*)(hpA + t * 512);
        const float4 hB = *(const float4*)(hpB + t * 512);
        const float4 wv = *(const float4*)(wp + t * 512);
        const float w4[4] = { wv.x, wv.y, wv.z, wv.w };
        #pragma unroll
        for (int ci = 0; ci < 4; ci++) {
          const float w = w4[ci];
          a[ci][0] += w * hA.x; a[ci][1] += w * hA.y;
          a[ci][2] += w * hA.z; a[ci][3] += w * hA.w;
          a[ci][4] += w * hB.x; a[ci][5] += w * hB.y;
          a[ci][6] += w * hB.z; a[ci][7] += w * hB.w;
        }
      }
      #pragma unroll
      for (int ci = 0; ci < 4; ci++) {
        #pragma unroll
        for (int bi = 0; bi < 8; bi++) {
          float v = a[ci][bi];
          v += dpp_xor1(v);
          v += dpp_xor2(v);
          v += dpp_ror4(v);
          v += dpp_ror8(v);
          a[ci][bi] = v;
        }
      }
      float g0 = 0.f, g1 = 0.f;
      #pragma unroll
      for (int ci = 0; ci < 4; ci++) {
        #pragma unroll
        for (int bq = 0; bq < 4; bq++) {
          if ((kp & 3) == ci && (kp >> 2) == bq) { g0 = a[ci][bq]; g1 = a[ci][bq + 4]; }
        }
      }
      gates[(b0 + (kp >> 2)) * 34 + c0 + (kp & 3)] = g0;
      gates[(b0 + 4 + (kp >> 2)) * 34 + c0 + (kp & 3)] = g1;
      __syncthreads();

      if (tid < 256) {
        const float gi = gates[nb * 34 + njl];
        const float gf = gates[nb * 34 + 8 + njl];
        const float gg = gates[nb * 34 + 16 + njl];
        const float go = gates[nb * 34 + 24 + njl];
        const float iv = sigmoidf_(gi + bb0);
        const float fv = sigmoidf_(gf + bb1);
        const float gv = tanhf(gg + bb2);
        const float ov = sigmoidf_(go + bb3);
        const float cnew = fv * creg + iv * gv;
        const float hnew = ov * tanhf(cnew);
        const bool valid = p < len_b;
        const int kold = 128 + j0 + njl;
        const float hold = hs[(kold << 5) + (nb ^ ((kold & 7) << 2))];
        const float houtv = valid ? hnew : hold;
        if (valid) creg = cnew;
        gstore(h0T + (size_t)(p & 3) * 8192 + (j0 + njl) * 32 + nb, houtv);
      }
    }

    __syncthreads();
    if (tid == 0)
      __hip_atomic_store(arr + bid * 32, (unsigned)(p + 1), __ATOMIC_RELEASE,
                         __HIP_MEMORY_SCOPE_AGENT);
  }
  // keep flag advancing so L1's "all >= p" style waits can't starve: final
  // flag after last phase is T_LEN (released above at p = T_LEN-1). L1 only
  // ever waits L0 >= min(p+1, 256) <= 256 ✓.
}

// ---------------------------------------------------------------------------
// Kernel 2, L1 body: SPLIT-GEMM PIPELINE (new this round).
// Phase p: (A) wait L0>=p+1 (near-free: L0 runs 2 ahead), stage h0[p],
// compute ih[s=p] = Wih1-half (t=0..15) into registers 'an'. (B) wait
// L1>=p (propagation hidden under A), stage h1[p-2], run hh-half
// (t=16..31) ACCUMULATING into 'apv' (= ih[s=p-1] saved last phase),
// butterfly/publish/nonlin for step s=p-1. Then apv <- an.
// Per-lane FMA order = ih terms (t 0..15) then hh (t 16..31): identical to
// R9's t=0..31 loop => bit-identical, absmax 0.0.
// Safety: L1 reads h0[p&3] at phase p; L0 overwrites slot at phase p+4
// gated on L1>=p+2 => read complete. h1 ring: hh-wait L1>=p serializes
// peers exactly as R9. Release discipline unchanged.
// ---------------------------------------------------------------------------
__device__ __forceinline__ void lstm_body_l1(
    const int j0,
    const float* __restrict__ Wih, const float* __restrict__ Whh,
    const float* __restrict__ bih, const float* __restrict__ bhh,
    const int* __restrict__ lens,
    float* __restrict__ h0T, float* __restrict__ h1T,
    unsigned* __restrict__ arr, const int bid,
    float* __restrict__ wlds, float* __restrict__ hs, float* __restrict__ gates)
{
  const int tid = threadIdx.x;
  const int kp = tid & 15;
  const int cg = (tid >> 4) & 7;
  const int bg = tid >> 7;
  const int c0 = cg * 4;
  const int b0 = bg * 8;
  const int sw = (kp & 7) << 2;
  const float* hpA = hs + kp * 32 + (b0 ^ sw);
  const float* hpB = hs + kp * 32 + ((b0 + 4) ^ sw);
  const float* wp  = wlds + kp * 32 + (c0 ^ sw);

  // one-time: weights -> LDS (rows [0,256)=Wih1, [256,512)=Whh1), swizzled
  for (int c = 0; c < 32; c++) {
    const int r = ((c >> 3) << 8) + j0 + (c & 7);
    {
      const int k = tid;
      float v = (k < 256) ? Wih[r * 256 + k] : Whh[r * 256 + (k - 256)];
      wlds[k * 32 + (c ^ ((k & 7) << 2))] = v;
    }
  }

  const int nb = tid >> 3, njl = tid & 7;
  float bb0 = 0.f, bb1 = 0.f, bb2 = 0.f, bb3 = 0.f;
  int len_b = T_LEN;
  if (tid < 256) {
    const int j = j0 + njl;
    bb0 = bih[j]       + bhh[j];
    bb1 = bih[256 + j] + bhh[256 + j];
    bb2 = bih[512 + j] + bhh[512 + j];
    bb3 = bih[768 + j] + bhh[768 + j];
    len_b = read_len(lens, nb);
  }
  float creg = 0.f;
  float apv[4][8];   // ih partial for the step finished THIS phase
  float an[4][8];    // ih partial computed this phase (for next)

  for (int p = 0; p <= T_LEN; p++) {
    // ---- (A) ih precompute for step s=p (needs h0[p]; L0 runs ahead) ----
    if (p < T_LEN) {
      dwait_half(arr, 0, p + 1);               // L0 flags >= p+1
      const float* s0 = h0T + (size_t)(p & 3) * 8192;
      #pragma unroll
      for (int i = tid; i < 2048; i += 512) {  // rows [0,256)
        const int k = i >> 3, b4 = (i & 7) << 2;
        const float4 v = *(const float4*)(s0 + (k << 5) + b4);
        *(float4*)(hs + (k << 5) + (b4 ^ ((k & 7) << 2))) = v;
      }
      __syncthreads();
      #pragma unroll
      for (int ci = 0; ci < 4; ci++)
        #pragma unroll
        for (int bi = 0; bi < 8; bi++) an[ci][bi] = 0.f;
      #pragma unroll
      for (int t = 0; t < 16; t++) {           // k = kp + 16t < 256
        const float4 hA = *(const float4*)(hpA + t * 512);
        const float4 hB = *(const float4*)(hpB + t * 512);
        const float4 wv = *(const float4*)(wp + t * 512);
        const float w4[4] = { wv.x, wv.y, wv.z, wv.w };
        #pragma unroll
        for (int ci = 0; ci < 4; ci++) {
          const float w = w4[ci];
          an[ci][0] += w * hA.x; an[ci][1] += w * hA.y;
          an[ci][2] += w * hA.z; an[ci][3] += w * hA.w;
          an[ci][4] += w * hB.x; an[ci][5] += w * hB.y;
          an[ci][6] += w * hB.z; an[ci][7] += w * hB.w;
        }
      }
    }

    // ---- (B) finish step s=p-1: hh-half + bias/nonlin/publish ----
    if (p >= 1) {
      dwait_half(arr, 32, p);                  // L1 flags >= p (hidden by A)
      const float* s1 = h1T + (size_t)((p + 2) & 3) * 8192;  // (p-2)&3
      #pragma unroll
      for (int i = tid; i < 2048; i += 512) {  // rows [256,512)
        const int k = i >> 3, b4 = (i & 7) << 2;
        const int kk = 256 + k;
        const float4 v = *(const float4*)(s1 + (k << 5) + b4);
        *(float4*)(hs + (kk << 5) + (b4 ^ ((k & 7) << 2))) = v;
      }
      __syncthreads();
      #pragma unroll
      for (int t = 16; t < 32; t++) {          // k = kp + 16t in [256,512)
        const float4 hA = *(const float4*)(hpA + t * 512);
        const float4 hB = *(const float4*)(hpB + t * 512);
        const float4 wv = *(const float4*)(wp + t * 512);
        const float w4[4] = { wv.x, wv.y, wv.z, wv.w };
        #pragma unroll
        for (int ci = 0; ci < 4; ci++) {
          const float w = w4[ci];
          apv[ci][0] += w * hA.x; apv[ci][1] += w * hA.y;
          apv[ci][2] += w * hA.z; apv[ci][3] += w * hA.w;
          apv[ci][4] += w * hB.x; apv[ci][5] += w * hB.y;
          apv[ci][6] += w * hB.z; apv[ci][7] += w * hB.w;
        }
      }
      #pragma unroll
      for (int ci = 0; ci < 4; ci++) {
        #pragma unroll
        for (int bi = 0; bi < 8; bi++) {
          float v = apv[ci][bi];
          v += dpp_xor1(v);
          v += dpp_xor2(v);
          v += dpp_ror4(v);
          v += dpp_ror8(v);
          apv[ci][bi] = v;
        }
      }
      float g0 = 0.f, g1 = 0.f;
      #pragma unroll
      for (int ci = 0; ci < 4; ci++) {
        #pragma unroll
        for (int bq = 0; bq < 4; bq++) {
          if ((kp & 3) == ci && (kp >> 2) == bq) { g0 = apv[ci][bq]; g1 = apv[ci][bq + 4]; }
        }
      }
      gates[(b0 + (kp >> 2)) * 34 + c0 + (kp & 3)] = g0;
      gates[(b0 + 4 + (kp >> 2)) * 34 + c0 + (kp & 3)] = g1;
      __syncthreads();

      if (tid < 256) {
        const float gi = gates[nb * 34 + njl];
        const float gf = gates[nb * 34 + 8 + njl];
        const float gg = gates[nb * 34 + 16 + njl];
        const float go = gates[nb * 34 + 24 + njl];
        const float iv = sigmoidf_(gi + bb0);
        const float fv = sigmoidf_(gf + bb1);
        const float gv = tanhf(gg + bb2);
        const float ov = sigmoidf_(go + bb3);
        const float cnew = fv * creg + iv * gv;
        const float hnew = ov * tanhf(cnew);
        const bool valid = (p - 1) < len_b;
        const int kold = 256 + j0 + njl;       // h1[p-2] row (frozen hold)
        const float hold = hs[(kold << 5) + (nb ^ ((kold & 7) << 2))];
        const float houtv = valid ? hnew : hold;
        if (valid) creg = cnew;
        gstore(h1T + (size_t)((p + 3) & 3) * 8192 + (j0 + njl) * 32 + nb, houtv);
      }
    }

    // rotate ih partials: the one computed this phase finishes next phase
    if (p < T_LEN) {
      #pragma unroll
      for (int ci = 0; ci < 4; ci++)
        #pragma unroll
        for (int bi = 0; bi < 8; bi++) apv[ci][bi] = an[ci][bi];
    }

    __syncthreads();   // drain stores before release
    if (tid == 0)
      __hip_atomic_store(arr + bid * 32, (unsigned)(p + 1), __ATOMIC_RELEASE,
                         __HIP_MEMORY_SCOPE_AGENT);
  }
}

__global__ __launch_bounds__(512) void lstm_pipe(
    const float* __restrict__ xT,
    const float* __restrict__ Wih0, const float* __restrict__ Whh0,
    const float* __restrict__ bih0, const float* __restrict__ bhh0,
    const float* __restrict__ Wih1, const float* __restrict__ Whh1,
    const float* __restrict__ bih1, const float* __restrict__ bhh1,
    const int* __restrict__ lens,
    const float* __restrict__ clfw, const float* __restrict__ clfb,
    float* __restrict__ ws, float* __restrict__ out)
{
  __shared__ float wlds[16384];        // [K][32] swizzled weights (64 KB)
  __shared__ float hs[16384];          // [K][32] swizzled inputs (64 KB)
  __shared__ float gates[32 * 34 + 2]; // [b][c], pad 34

  unsigned* arr = (unsigned*)ws;       // flag array: 64 x 128B stride
  float* h0T = ws + 2048;              // [4][256*32] quad-buffered h0
  float* h1T = ws + 2048 + 32768;      // [4][256*32] quad-buffered h1

  const int bid = blockIdx.x;
  if (bid >= 32)
    lstm_body_l1((bid - 32) * 8, Wih1, Whh1, bih1, bhh1, lens,
                 h0T, h1T, arr, bid, wlds, hs, gates);
  else
    lstm_body_l0(bid * 8, xT, Wih0, Whh0, bih0, bhh0, lens,
                 h0T, h1T, arr, bid, wlds, hs, gates);

  // classifier: h1[255] lives in buf[255&3] = 3, published at L1 phase 256.
  if (bid == 0) {
    const int tid = threadIdx.x;
    dwait(arr, 0, T_LEN + 1);          // all L1 flags >= 257
    const float* h1f = h1T + (size_t)3 * 8192;
    if (tid < 256) {
      const int b = tid & 31, jg = tid >> 5;
      float s = 0.f;
      #pragma unroll 8
      for (int jj = 0; jj < 32; jj++) {
        const int j = jg * 32 + jj;
        s += gload(h1f + j * 32 + b) * clfw[j];
      }
      gates[jg * 32 + b] = s;
    }
    __syncthreads();
    if (tid < 32) {
      float s = clfb[0];
      #pragma unroll
      for (int g = 0; g < 8; g++) s += gates[g * 32 + tid];
      out[tid] = s;
    }
  }
}

// ---------------------------------------------------------------------------
extern "C" void kernel_launch(void* const* d_in, const int* in_sizes, int n_in,
                              void* d_out, int out_size, void* d_ws, size_t ws_size,
                              hipStream_t stream) {
  (void)in_sizes; (void)n_in; (void)out_size; (void)ws_size;
  const float* feat = (const float*)d_in[0];
  const int*   lens = (const int*)d_in[1];
  const float* W1   = (const float*)d_in[2];
  const float* as1  = (const float*)d_in[3];
  const float* ad1  = (const float*)d_in[4];
  const float* b1   = (const float*)d_in[5];
  const float* W2   = (const float*)d_in[6];
  const float* as2  = (const float*)d_in[7];
  const float* ad2  = (const float*)d_in[8];
  const float* b2   = (const float*)d_in[9];
  const float* Wih0 = (const float*)d_in[10];
  const float* Whh0 = (const float*)d_in[11];
  const float* bih0 = (const float*)d_in[12];
  const float* bhh0 = (const float*)d_in[13];
  const float* Wih1 = (const float*)d_in[14];
  const float* Whh1 = (const float*)d_in[15];
  const float* bih1 = (const float*)d_in[16];
  const float* bhh1 = (const float*)d_in[17];
  const float* clfw = (const float*)d_in[18];
  const float* clfb = (const float*)d_in[19];

  float* ws  = (float*)d_ws;
  float* xT  = ws + 2048 + 65536;   // [256 t][128 c][32 b] = 4 MB
  float* outp = (float*)d_out;

  // zero barrier flags + h0/h1 quad buffers (2048 + 2*4*8192 floats)
  hipMemsetAsync(d_ws, 0, (2048 + 65536) * sizeof(float), stream);

  gat_naive<<<8192, 256, 0, stream>>>(feat, lens, W1, as1, ad1, b1,
                                      W2, as2, ad2, b2, xT);

  void* args[] = {
    (void*)&xT,
    (void*)&Wih0, (void*)&Whh0, (void*)&bih0, (void*)&bhh0,
    (void*)&Wih1, (void*)&Whh1, (void*)&bih1, (void*)&bhh1,
    (void*)&lens, (void*)&clfw, (void*)&clfb, (void*)&ws, (void*)&outp
  };
  hipLaunchCooperativeKernel((const void*)lstm_pipe, dim3(NBLK_SEQ), dim3(512),
                             args, 0, stream);
}

// Round 12
// 3379.528 us; speedup vs baseline: 1.1255x; 1.1255x over previous
//
#include <hip/hip_runtime.h>
#include <math.h>

#define A_PL 22
#define F_IN_ 16
#define T_LEN 256
#define NBLK_SEQ 64

__device__ __forceinline__ float sigmoidf_(float x) { return 1.f / (1.f + __expf(-x)); }

// Cross-XCD-safe handoff (per-op agent-scope atomics; validated across rounds,
// absmax 0.0 every passing run).
__device__ __forceinline__ void gstore(float* p, float v) {
  __hip_atomic_store(p, v, __ATOMIC_RELAXED, __HIP_MEMORY_SCOPE_AGENT);
}
__device__ __forceinline__ float gload(const float* p) {
  return __hip_atomic_load(p, __ATOMIC_RELAXED, __HIP_MEMORY_SCOPE_AGENT);
}

// Dataflow wait (R4..R9-validated): acquire-poll + agent-acquire fence so
// subsequent PLAIN vector loads see released data.
__device__ __forceinline__ void dwait(unsigned* arr, int tlo, int thi) {
  if (threadIdx.x < 64) {
    const int lane = threadIdx.x;
    int t = (lane < 32) ? tlo : thi;
    if (t < 0) t = 0;
    const unsigned tu = (unsigned)t;
    while (__hip_atomic_load(arr + lane * 32, __ATOMIC_ACQUIRE,
                             __HIP_MEMORY_SCOPE_AGENT) < tu) {
      __builtin_amdgcn_s_sleep(1);
    }
  }
  __syncthreads();
  __builtin_amdgcn_fence(__ATOMIC_ACQUIRE, "agent");
}

// DPP cross-lane ops, all on the VALU pipe (no LDS). (R7/R9-validated.)
__device__ __forceinline__ float dpp_xor1(float v) {
  int r = __builtin_amdgcn_mov_dpp(__builtin_bit_cast(int, v), 0xB1, 0xF, 0xF, true);
  return __builtin_bit_cast(float, r);
}
__device__ __forceinline__ float dpp_xor2(float v) {
  int r = __builtin_amdgcn_mov_dpp(__builtin_bit_cast(int, v), 0x4E, 0xF, 0xF, true);
  return __builtin_bit_cast(float, r);
}
__device__ __forceinline__ float dpp_ror4(float v) {
  int r = __builtin_amdgcn_mov_dpp(__builtin_bit_cast(int, v), 0x124, 0xF, 0xF, true);
  return __builtin_bit_cast(float, r);
}
__device__ __forceinline__ float dpp_ror8(float v) {
  int r = __builtin_amdgcn_mov_dpp(__builtin_bit_cast(int, v), 0x128, 0xF, 0xF, true);
  return __builtin_bit_cast(float, r);
}

// seq_lengths: int64 or int32. True values in [128,256], never 0 =>
// little-endian int64 has lens32[1]==0.
__device__ __forceinline__ int read_len(const int* __restrict__ lens, int b) {
  return (lens[1] == 0) ? lens[2 * b] : lens[b];
}

// ---------------------------------------------------------------------------
// Kernel 1: fused GAT. R12 == R11 (unexercised due to infra flake): the
// per-head aggregation (alpha @ hbuf) retiled to c-QUADS: thread <-> (a, c4);
// inner j-loop reads hbuf[j*128+c4] as ONE b128 (4 columns) + 1 alpha b32
// broadcast => 44 LDS instr per FOUR outputs (was per one): 484 -> ~121 LDS
// instr/thread/head. Per-element j-order unchanged -> bit-identical
// (absmax 0.0 preserved). Everything else: R9 verbatim.
// Output written TRANSPOSED as xT[t][c][b].
// ---------------------------------------------------------------------------
__global__ __launch_bounds__(256) void gat_naive(
    const float* __restrict__ feat, const int* __restrict__ lens,
    const float* __restrict__ W1, const float* __restrict__ as1,
    const float* __restrict__ ad1, const float* __restrict__ b1,
    const float* __restrict__ W2, const float* __restrict__ as2,
    const float* __restrict__ ad2, const float* __restrict__ b2,
    float* __restrict__ xT)
{
  const int n = blockIdx.x;
  const int tid = threadIdx.x;
  const int bb = n >> 8;          // batch
  const int tt = n & 255;         // time
  if (tt >= read_len(lens, bb)) { // masked frame: pooled = 0
    if (tid < 128) xT[((size_t)tt * 128 + tid) * 32 + bb] = 0.f;
    return;
  }

  __shared__ float xs[352];       // x [22][16]
  __shared__ float hbuf[2816];    // per-head h [22][128]; later h2 [22][128]
  __shared__ float x2s[11264];    // GAT1 output [22][512] (relu'd)
  __shared__ float asrc[22], adst[22], alpha[484];

  for (int i = tid; i < 352; i += 256) xs[i] = feat[(size_t)n * 352 + i];
  __syncthreads();

  const int c_ = tid & 127;
  const int ap_ = tid >> 7;       // a-parity for this thread

  for (int hd = 0; hd < 4; hd++) {
    {
      float wreg[16];
      #pragma unroll
      for (int f = 0; f < 16; f++) wreg[f] = W1[f * 512 + hd * 128 + c_];
      #pragma unroll
      for (int q = 0; q < 11; q++) {
        const int a = ap_ + 2 * q;
        float acc = 0.f;
        #pragma unroll
        for (int f4 = 0; f4 < 4; f4++) {
          const float4 x4 = *(const float4*)(xs + a * 16 + f4 * 4);
          acc += x4.x * wreg[f4 * 4] + x4.y * wreg[f4 * 4 + 1]
               + x4.z * wreg[f4 * 4 + 2] + x4.w * wreg[f4 * 4 + 3];
        }
        hbuf[a * 128 + c_] = acc;
      }
    }
    __syncthreads();
    if (tid < 44) {
      int a = tid >> 1;
      const float* av = (tid & 1) ? ad1 : as1;
      float s = 0.f;
      for (int c = 0; c < 128; c++) s += hbuf[a * 128 + c] * av[hd * 128 + c];
      ((tid & 1) ? adst : asrc)[a] = s;
    }
    __syncthreads();
    if (tid < 22) {
      float ev[22], m = -1e30f;
      for (int j = 0; j < 22; j++) {
        float e = adst[tid] + asrc[j];
        e = (e > 0.f) ? e : 0.2f * e;
        ev[j] = e; if (e > m) m = e;
      }
      float s = 0.f;
      for (int j = 0; j < 22; j++) { ev[j] = __expf(ev[j] - m); s += ev[j]; }
      float inv = 1.f / s;
      for (int j = 0; j < 22; j++) alpha[tid * 22 + j] = ev[j] * inv;
    }
    __syncthreads();
    // ---- aggregation, c-quad float4 (R11): 704 quad-outputs ----
    for (int i = tid; i < 704; i += 256) {
      const int a = i >> 5, c4 = (i & 31) << 2;
      float4 acc = make_float4(0.f, 0.f, 0.f, 0.f);
      for (int j = 0; j < 22; j++) {
        const float al = alpha[a * 22 + j];
        const float4 h4 = *(const float4*)(hbuf + j * 128 + c4);
        acc.x += al * h4.x; acc.y += al * h4.y;
        acc.z += al * h4.z; acc.w += al * h4.w;
      }
      const float4 bv = *(const float4*)(b1 + hd * 128 + c4);
      float4 o;
      o.x = fmaxf(acc.x + bv.x, 0.f);
      o.y = fmaxf(acc.y + bv.y, 0.f);
      o.z = fmaxf(acc.z + bv.z, 0.f);
      o.w = fmaxf(acc.w + bv.w, 0.f);
      *(float4*)(x2s + a * 512 + hd * 128 + c4) = o;
    }
    __syncthreads();
  }

  // ---- W2 matmul: hbuf = relu-in of GAT2 h = x2s @ W2 (R9 verbatim) ----
  {
    float acc[11];
    #pragma unroll
    for (int q = 0; q < 11; q++) acc[q] = 0.f;
    for (int k = 0; k < 512; k += 4) {
      const float w0 = W2[(size_t)(k + 0) * 128 + c_];
      const float w1 = W2[(size_t)(k + 1) * 128 + c_];
      const float w2 = W2[(size_t)(k + 2) * 128 + c_];
      const float w3 = W2[(size_t)(k + 3) * 128 + c_];
      #pragma unroll
      for (int q = 0; q < 11; q++) {
        const float4 x4 = *(const float4*)(x2s + (ap_ + 2 * q) * 512 + k);
        acc[q] += x4.x * w0 + x4.y * w1 + x4.z * w2 + x4.w * w3;
      }
    }
    #pragma unroll
    for (int q = 0; q < 11; q++) hbuf[(ap_ + 2 * q) * 128 + c_] = acc[q];
  }
  __syncthreads();
  if (tid < 44) {
    int a = tid >> 1;
    const float* av = (tid & 1) ? ad2 : as2;
    float s = 0.f;
    for (int c = 0; c < 128; c++) s += hbuf[a * 128 + c] * av[c];
    ((tid & 1) ? adst : asrc)[a] = s;
  }
  __syncthreads();
  if (tid < 22) {
    float ev[22], m = -1e30f;
    for (int j = 0; j < 22; j++) {
      float e = adst[tid] + asrc[j];
      e = (e > 0.f) ? e : 0.2f * e;
      ev[j] = e; if (e > m) m = e;
    }
    float s = 0.f;
    for (int j = 0; j < 22; j++) { ev[j] = __expf(ev[j] - m); s += ev[j]; }
    float inv = 1.f / s;
    for (int j = 0; j < 22; j++) alpha[tid * 22 + j] = ev[j] * inv;
  }
  __syncthreads();
  if (tid < 128) {
    float s = 0.f;
    for (int a = 0; a < 22; a++) {
      float v = b2[tid];
      for (int j = 0; j < 22; j++) v += alpha[a * 22 + j] * hbuf[j * 128 + tid];
      s += fmaxf(v, 0.f);
    }
    xT[((size_t)tt * 128 + tid) * 32 + bb] = s * (1.f / 22.f);
  }
}

// ---------------------------------------------------------------------------
// Kernel 2: LDS-weight batch-32 GEMM LSTM, dataflow sync. R9 VERBATIM
// (passed, 2523us, absmax 0.0). R10's split-GEMM pipeline regressed
// (2894us: extra barriers + halved staging MLP) and is reverted.
// wlds[k][c ^ ((k&7)<<2)] XOR-swizzle (R9-validated: conflicts 7.7e7->3.25e7).
// Tiling: thread = (kp 0..15, cg 0..7, bg 0..3): c-tile 4, b-tile 8, 16-way
// K-split. Quad-buffered h0T/h1T agent handoff; per-block monotonic flags;
// L0@p waits {L0>=p, L1>=p-2}; L1@p waits {all>=p}; release after
// __syncthreads. Butterfly fully DPP. LDS: 64+64+4.4 = 133KB, 1 blk/CU.
// ---------------------------------------------------------------------------
template<int KK>
__device__ __forceinline__ void lstm_body(
    const int j0, const float* __restrict__ xT,
    const float* __restrict__ Wih, const float* __restrict__ Whh,
    const float* __restrict__ bih, const float* __restrict__ bhh,
    const int* __restrict__ lens,
    float* __restrict__ h0T, float* __restrict__ h1T,
    unsigned* __restrict__ arr, const int bid,
    float* __restrict__ wlds, float* __restrict__ hs, float* __restrict__ gates)
{
  constexpr int NK = KK / 16;           // 24 (L0) / 32 (L1)
  constexpr bool IS1 = (KK == 512);
  const int tid = threadIdx.x;
  const int kp = tid & 15;
  const int cg = (tid >> 4) & 7;
  const int bg = tid >> 7;
  const int c0 = cg * 4;
  const int b0 = bg * 8;
  const int sw = (kp & 7) << 2;
  const float* hpA = hs + kp * 32 + (b0 ^ sw);
  const float* hpB = hs + kp * 32 + ((b0 + 4) ^ sw);
  const float* wp  = wlds + kp * 32 + (c0 ^ sw);   // swizzled weight read

  // ---- one-time: weights -> LDS wlds[k][c ^ ((k&7)<<2)], c = gate*8+jl ----
  for (int c = 0; c < 32; c++) {
    const int r = ((c >> 3) << 8) + j0 + (c & 7);
    for (int k = tid; k < KK; k += 512) {
      float v;
      if (IS1) v = (k < 256) ? Wih[r * 256 + k] : Whh[r * 256 + (k - 256)];
      else     v = (k < 128) ? Wih[r * 128 + k] : Whh[r * 256 + (k - 128)];
      wlds[k * 32 + (c ^ ((k & 7) << 2))] = v;
    }
  }

  // nonlinearity mapping (tid < 256): thread = (batch nb, local j njl)
  const int nb = tid >> 3, njl = tid & 7;
  float bb0 = 0.f, bb1 = 0.f, bb2 = 0.f, bb3 = 0.f;
  int len_b = T_LEN;
  if (tid < 256) {
    const int j = j0 + njl;
    bb0 = bih[j]       + bhh[j];
    bb1 = bih[256 + j] + bhh[256 + j];
    bb2 = bih[512 + j] + bhh[512 + j];
    bb3 = bih[768 + j] + bhh[768 + j];
    len_b = read_len(lens, nb);
  }
  float creg = 0.f;

  const int PMAX = IS1 ? T_LEN : (T_LEN - 1);
  for (int p = 0; p <= PMAX; p++) {
    if (p > 0) dwait(arr, p, IS1 ? p : p - 2);
    const bool compute = IS1 ? (p >= 1) : true;

    if (compute) {
      // ---- stage inputs into hs (plain float4; swizzled LDS writes) ----
      if (IS1) {
        const float* s0 = h0T + (size_t)((p - 1) & 3) * 8192;
        const float* s1 = h1T + (size_t)((p + 2) & 3) * 8192;  // (p-2)&3
        #pragma unroll
        for (int i = tid; i < 4096; i += 512) {
          const int k = i >> 3, b4 = (i & 7) << 2;
          const float4 v = (k < 256)
              ? *(const float4*)(s0 + (k << 5) + b4)
              : *(const float4*)(s1 + ((k - 256) << 5) + b4);
          *(float4*)(hs + (k << 5) + (b4 ^ ((k & 7) << 2))) = v;
        }
      } else {
        const float* xp = xT + (size_t)p * 4096;
        const float* s0 = h0T + (size_t)((p + 3) & 3) * 8192;  // (p-1)&3
        #pragma unroll
        for (int i = tid; i < 3072; i += 512) {
          const int k = i >> 3, b4 = (i & 7) << 2;
          const float4 v = (k < 128)
              ? *(const float4*)(xp + (k << 5) + b4)
              : *(const float4*)(s0 + ((k - 128) << 5) + b4);
          *(float4*)(hs + (k << 5) + (b4 ^ ((k & 7) << 2))) = v;
        }
      }
      __syncthreads();   // also orders the one-time wlds writes before GEMM

      // ---- [32b x 32c] x K GEMM: w + h from LDS (both swizzled) ----
      float a[4][8] = {};
      #pragma unroll
      for (int t = 0; t < NK; t++) {
        const float4 hA = *(const float4*)(hpA + t * 512);
        const float4 hB = *(const float4*)(hpB + t * 512);
        const float4 wv = *(const float4*)(wp + t * 512);
        const float w4[4] = { wv.x, wv.y, wv.z, wv.w };
        #pragma unroll
        for (int ci = 0; ci < 4; ci++) {
          const float w = w4[ci];
          a[ci][0] += w * hA.x; a[ci][1] += w * hA.y;
          a[ci][2] += w * hA.z; a[ci][3] += w * hA.w;
          a[ci][4] += w * hB.x; a[ci][5] += w * hB.y;
          a[ci][6] += w * hB.z; a[ci][7] += w * hB.w;
        }
      }
      // K-split reduce across 16 kp lanes, all on DPP (VALU pipe)
      #pragma unroll
      for (int ci = 0; ci < 4; ci++) {
        #pragma unroll
        for (int bi = 0; bi < 8; bi++) {
          float v = a[ci][bi];
          v += dpp_xor1(v);
          v += dpp_xor2(v);
          v += dpp_ror4(v);
          v += dpp_ror8(v);
          a[ci][bi] = v;
        }
      }
      // lane kp publishes (c0+(kp&3), b0+(kp>>2)) and (.., b0+4+(kp>>2))
      float g0 = 0.f, g1 = 0.f;
      #pragma unroll
      for (int ci = 0; ci < 4; ci++) {
        #pragma unroll
        for (int bq = 0; bq < 4; bq++) {
          if ((kp & 3) == ci && (kp >> 2) == bq) { g0 = a[ci][bq]; g1 = a[ci][bq + 4]; }
        }
      }
      gates[(b0 + (kp >> 2)) * 34 + c0 + (kp & 3)] = g0;
      gates[(b0 + 4 + (kp >> 2)) * 34 + c0 + (kp & 3)] = g1;
      __syncthreads();

      if (tid < 256) {
        const float gi = gates[nb * 34 + njl];
        const float gf = gates[nb * 34 + 8 + njl];
        const float gg = gates[nb * 34 + 16 + njl];
        const float go = gates[nb * 34 + 24 + njl];
        const float iv = sigmoidf_(gi + bb0);
        const float fv = sigmoidf_(gf + bb1);
        const float gv = tanhf(gg + bb2);
        const float ov = sigmoidf_(go + bb3);
        const float cnew = fv * creg + iv * gv;
        const float hnew = ov * tanhf(cnew);
        const int t_eff = IS1 ? (p - 1) : p;
        const bool valid = t_eff < len_b;
        // frozen republish past seq len: previous h from staged hs
        const int kold = (IS1 ? 256 : 128) + j0 + njl;
        const float hold = hs[(kold << 5) + (nb ^ ((kold & 7) << 2))];
        const float houtv = valid ? hnew : hold;
        if (valid) creg = cnew;
        float* dst = (IS1 ? h1T + (size_t)((p + 3) & 3) * 8192    // (p-1)&3
                          : h0T + (size_t)(p & 3) * 8192)
                     + (j0 + njl) * 32 + nb;
        gstore(dst, houtv);
      }
    }

    __syncthreads();   // drain all waves' stores before the release
    if (tid == 0)
      __hip_atomic_store(arr + bid * 32, (unsigned)(p + 1), __ATOMIC_RELEASE,
                         __HIP_MEMORY_SCOPE_AGENT);
  }
}

__global__ __launch_bounds__(512) void lstm_pipe(
    const float* __restrict__ xT,
    const float* __restrict__ Wih0, const float* __restrict__ Whh0,
    const float* __restrict__ bih0, const float* __restrict__ bhh0,
    const float* __restrict__ Wih1, const float* __restrict__ Whh1,
    const float* __restrict__ bih1, const float* __restrict__ bhh1,
    const int* __restrict__ lens,
    const float* __restrict__ clfw, const float* __restrict__ clfb,
    float* __restrict__ ws, float* __restrict__ out)
{
  __shared__ float wlds[16384];        // [K][32] swizzled weights (64 KB)
  __shared__ float hs[16384];          // [K][32] swizzled inputs (64 KB)
  __shared__ float gates[32 * 34 + 2]; // [b][c], pad 34

  unsigned* arr = (unsigned*)ws;       // flag array: 64 x 128B stride
  float* h0T = ws + 2048;              // [4][256*32] quad-buffered h0
  float* h1T = ws + 2048 + 32768;      // [4][256*32] quad-buffered h1

  const int bid = blockIdx.x;
  if (bid >= 32)
    lstm_body<512>((bid - 32) * 8, xT, Wih1, Whh1, bih1, bhh1, lens,
                   h0T, h1T, arr, bid, wlds, hs, gates);
  else
    lstm_body<384>(bid * 8, xT, Wih0, Whh0, bih0, bhh0, lens,
                   h0T, h1T, arr, bid, wlds, hs, gates);

  // classifier: h1[255] lives in buf[255&3] = 3, published at L1 phase 256.
  if (bid == 0) {
    const int tid = threadIdx.x;
    dwait(arr, 0, T_LEN + 1);          // all L1 flags >= 257
    const float* h1f = h1T + (size_t)3 * 8192;
    if (tid < 256) {
      const int b = tid & 31, jg = tid >> 5;
      float s = 0.f;
      #pragma unroll 8
      for (int jj = 0; jj < 32; jj++) {
        const int j = jg * 32 + jj;
        s += gload(h1f + j * 32 + b) * clfw[j];
      }
      gates[jg * 32 + b] = s;
    }
    __syncthreads();
    if (tid < 32) {
      float s = clfb[0];
      #pragma unroll
      for (int g = 0; g < 8; g++) s += gates[g * 32 + tid];
      out[tid] = s;
    }
  }
}

// ---------------------------------------------------------------------------
extern "C" void kernel_launch(void* const* d_in, const int* in_sizes, int n_in,
                              void* d_out, int out_size, void* d_ws, size_t ws_size,
                              hipStream_t stream) {
  (void)in_sizes; (void)n_in; (void)out_size; (void)ws_size;
  const float* feat = (const float*)d_in[0];
  const int*   lens = (const int*)d_in[1];
  const float* W1   = (const float*)d_in[2];
  const float* as1  = (const float*)d_in[3];
  const float* ad1  = (const float*)d_in[4];
  const float* b1   = (const float*)d_in[5];
  const float* W2   = (const float*)d_in[6];
  const float* as2  = (const float*)d_in[7];
  const float* ad2  = (const float*)d_in[8];
  const float* b2   = (const float*)d_in[9];
  const float* Wih0 = (const float*)d_in[10];
  const float* Whh0 = (const float*)d_in[11];
  const float* bih0 = (const float*)d_in[12];
  const float* bhh0 = (const float*)d_in[13];
  const float* Wih1 = (const float*)d_in[14];
  const float* Whh1 = (const float*)d_in[15];
  const float* bih1 = (const float*)d_in[16];
  const float* bhh1 = (const float*)d_in[17];
  const float* clfw = (const float*)d_in[18];
  const float* clfb = (const float*)d_in[19];

  float* ws  = (float*)d_ws;
  float* xT  = ws + 2048 + 65536;   // [256 t][128 c][32 b] = 4 MB
  float* outp = (float*)d_out;

  // zero barrier flags + h0/h1 quad buffers (2048 + 2*4*8192 floats)
  hipMemsetAsync(d_ws, 0, (2048 + 65536) * sizeof(float), stream);

  gat_naive<<<8192, 256, 0, stream>>>(feat, lens, W1, as1, ad1, b1,
                                      W2, as2, ad2, b2, xT);

  void* args[] = {
    (void*)&xT,
    (void*)&Wih0, (void*)&Whh0, (void*)&bih0, (void*)&bhh0,
    (void*)&Wih1, (void*)&Whh1, (void*)&bih1, (void*)&bhh1,
    (void*)&lens, (void*)&clfw, (void*)&clfb, (void*)&ws, (void*)&outp
  };
  hipLaunchCooperativeKernel((const void*)lstm_pipe, dim3(NBLK_SEQ), dim3(512),
                             args, 0, stream);
}